// Round 8
// baseline (1414.465 us; speedup 1.0000x reference)
//
#include <hip/hip_runtime.h>

#define SEQL 1024
#define BATCHN 128
#define UNITS 256
#define INDIM 128
#define G3 768   // r|u|h gate columns

typedef __attribute__((ext_vector_type(8))) short short8;
typedef __attribute__((ext_vector_type(4))) short short4v;
typedef __attribute__((ext_vector_type(4))) float floatx4;

#define NL2E  -1.4426950408889634f   // -log2(e): r,u gate scale
#define PL2E2  2.8853900817779268f   //  2*log2(e): h gate scale

#define HSTRIDE 272                  // compact h row stride (shorts), breaks bank alias

__device__ __forceinline__ short f2bf(float f) {
  unsigned u = __float_as_uint(f);
  u += 0x7fff + ((u >> 16) & 1);   // round-to-nearest-even
  return (short)(u >> 16);
}
__device__ __forceinline__ float bf2f(unsigned short s) {
  return __uint_as_float(((unsigned)s) << 16);
}
__device__ __forceinline__ float fexp2(float x) {
#if __has_builtin(__builtin_amdgcn_exp2f)
  return __builtin_amdgcn_exp2f(x);
#else
  return __expf(0.6931471805599453f * x);
#endif
}
__device__ __forceinline__ float frcp(float x) {
#if __has_builtin(__builtin_amdgcn_rcpf)
  return __builtin_amdgcn_rcpf(x);
#else
  return 1.f / x;
#endif
}

// LDS-only barrier: orders ds ops without draining vmcnt.
#define LDS_BARRIER() do {                                   \
    asm volatile("s_waitcnt lgkmcnt(0)" ::: "memory");       \
    __builtin_amdgcn_s_barrier();                            \
    asm volatile("" ::: "memory");                           \
  } while (0)

// Opaque pin: downstream users consume the ASM OUTPUT, not the load result,
// so the load cannot be rematerialized per-use. R2/R3 applied this under a
// 128-VGPR cap (launch_bounds(512,2)) where 192 resident regs could never
// fit -> scratch disaster. R7 moved to launch_bounds(512,1) = 256-reg cap;
// pinning wR+wU (128 regs, peak ~200 total) now fits without spills.
#define PIN8(x) asm volatile("" : "+v"(x))

// Acquire-spin on a producer flag.
__device__ __forceinline__ void acq_spin(const int* p) {
  while (__hip_atomic_load(p, __ATOMIC_ACQUIRE, __HIP_MEMORY_SCOPE_AGENT) == 0)
    __builtin_amdgcn_s_sleep(8);
}

// ---------------------------------------------------------------------------
// Kernel A: weight prep (unchanged math) + zeroing the 1024 producer flags.
// ---------------------------------------------------------------------------
__global__ void prep_kernel(const float* __restrict__ iw,   // (128,1792)
                            const float* __restrict__ hw,   // (256,768)
                            short* __restrict__ WcB, short* __restrict__ WhB,
                            int* __restrict__ flags) {
  int idx = blockIdx.x * 256 + threadIdx.x;
  const int WCN = 384 * G3;
  if (idx < WCN) {
    int k = idx / G3, n = idx % G3;
    int i = k & 127, blkk = k >> 7;      // 0:x_t 1:x_{t-1} 2:x_{t-2}
    int gsel = n >> 8, c = n & 255;      // 0:r 1:u 2:h
    const float* row = iw + (size_t)i * 1792;
    float v;
    if (blkk == 0) {
      v = (gsel == 0) ? row[c] + row[768 + c] + row[1280 + c]
        : (gsel == 1) ? row[256 + c] + row[1024 + c] + row[1536 + c]
                      : row[512 + c];
    } else if (blkk == 1) {
      v = (gsel == 0) ? -(row[768 + c] + 2.f * row[1280 + c])
        : (gsel == 1) ? -(row[1024 + c] + 2.f * row[1536 + c])
                      : 0.f;
    } else {
      v = (gsel == 0) ? row[1280 + c]
        : (gsel == 1) ? row[1536 + c]
                      : 0.f;
    }
    v *= (gsel == 2) ? PL2E2 : NL2E;
    int kk = k >> 5, q = (k >> 3) & 3, j = k & 7;
    WcB[(((n * 12 + kk) * 4 + q) * 8) + j] = f2bf(v);
  } else {
    idx -= WCN;
    if (idx < 256 * G3) {
      int k = idx / G3, n = idx % G3;
      float v = hw[(size_t)k * G3 + n] * ((n >> 8) == 2 ? PL2E2 : NL2E);
      int kk = k >> 5, q = (k >> 3) & 3, j = k & 7;
      WhB[(((n * 8 + kk) * 4 + q) * 8) + j] = f2bf(v);
    } else {
      idx -= 256 * G3;
      if (idx < SEQL) flags[idx] = 0;
    }
  }
}

// ---------------------------------------------------------------------------
// Fused kernel, 1 block/CU enforced by ~100 KB static LDS:
//  blocks 0..31  : persistent recurrence (consumer) — EXCLUSIVE CU each.
//  blocks 32..1055: input projection, ONE block per timestep t, M=128 (full
//  batch), weights amortized 8x via 96 KB LDS A-frag staging.
//  R8: rnn wR/wU fragments pinned resident (asm-opaque) under the 256-VGPR
//  cap — kills 2/3 of the 384 KB/CU/step WhB L2 re-stream; wH still streams
//  under phase-A latency cover.
// ---------------------------------------------------------------------------
__global__ __launch_bounds__(512, 1) void fused_kernel(
    const float* __restrict__ x, const short* __restrict__ WcB,
    const float* __restrict__ bias, unsigned* __restrict__ pre2,
    const short* __restrict__ WhB, float* __restrict__ out,
    int* __restrict__ flags) {
  __shared__ __align__(16) short xA[6144 * 8];       // 96 KB proj A-frags
  __shared__ __align__(16) short hFc[4 * HSTRIDE];   // rnn h (2.1 KB)
  __shared__ __align__(16) short rFc[4 * HSTRIDE];   // rnn r*h (2.1 KB)

  const int tid = threadIdx.x;

  if (blockIdx.x >= 32) {
    // =================== proj role: one block per t, M=128 ===================
    const int t = blockIdx.x - 32;

    // stage A[m][k] = x_hist[m][k] as MFMA A-frags for all 128 rows:
    // unit u (short8) holds A[mi*16+bb][kk*32+qq*8 .. +7] at xA[u*8],
    // u = (kk*8+mi)*64 + qq*16 + bb  (read addr: (kk*8+mi)*64 + lane).
#pragma unroll
    for (int it = 0; it < 12; ++it) {
      int u = it * 512 + tid;
      int kk8mi = u >> 6, l6 = u & 63;
      int kk = kk8mi >> 3, mi = kk8mi & 7;
      int qq = l6 >> 4, bb = l6 & 15;
      int row = mi * 16 + bb;
      int k = kk * 32 + qq * 8;
      int dt = k >> 7, kin = k & 127;          // dt: 0=x_t 1=x_{t-1} 2=x_{t-2}
      floatx4 v0 = {0.f, 0.f, 0.f, 0.f}, v1 = {0.f, 0.f, 0.f, 0.f};
      if (t >= dt) {
        const float* src = x + ((size_t)row * SEQL + (t - dt)) * INDIM + kin;
        v0 = *(const floatx4*)src;
        v1 = *(const floatx4*)(src + 4);
      }
      short8 pk;
#pragma unroll
      for (int j = 0; j < 4; ++j) { pk[j] = f2bf(v0[j]); pk[4 + j] = f2bf(v1[j]); }
      *(short8*)&xA[u * 8] = pk;
    }
    __syncthreads();

    const int w = tid >> 6, lane = tid & 63, ln16 = lane & 15, qp = lane >> 4;

    // wave w owns cols [w*96, w*96+96): 3 chunks of one col-pair (c, c+16)
#pragma unroll
    for (int j = 0; j < 3; ++j) {
      const int n0 = w * 96 + 32 * j;            // pair base (bit4 == 0)
      const int nA = n0 + ln16, nB = n0 + 16 + ln16;
      const int g = n0 >> 8;                     // gate 0:r 1:u 2:h
      const float sc = (g == 2) ? PL2E2 : NL2E;
      const int wvc = (n0 & 255) >> 5;           // consuming rnn wave

      short8 wA[12], wB[12];                     // resident weight frags
#pragma unroll
      for (int kk = 0; kk < 12; ++kk) {
        wA[kk] = *(const short8*)(WcB + (((size_t)(nA * 12 + kk) * 4 + qp) * 8));
        wB[kk] = *(const short8*)(WcB + (((size_t)(nB * 12 + kk) * 4 + qp) * 8));
      }
      const float bvA = bias[nA] * sc, bvB = bias[nB] * sc;

#pragma unroll
      for (int mi = 0; mi < 8; ++mi) {           // 8 m-tiles reuse wA/wB
        floatx4 aA = {bvA, bvA, bvA, bvA};
        floatx4 aB = {bvB, bvB, bvB, bvB};
#pragma unroll
        for (int kk = 0; kk < 12; ++kk) {
          const short8 a = *(const short8*)&xA[(((kk * 8 + mi) * 64) + lane) * 8];
          aA = __builtin_amdgcn_mfma_f32_16x16x32_bf16(a, wA[kk], aA, 0, 0, 0);
          aB = __builtin_amdgcn_mfma_f32_16x16x32_bf16(a, wB[kk], aB, 0, 0, 0);
        }
        // batch row = mi*16 + qp*4 + r  ->  rnn wg = mi*4+qp, row-in-wg = r
        unsigned* slab = pre2 + (size_t)((mi * 4 + qp) * SEQL + t) * 1536
                       + g * 512 + wvc * 64 + ln16;
#pragma unroll
        for (int r = 0; r < 4; ++r) {
          unsigned lo = (unsigned)(unsigned short)f2bf(aA[r]);
          unsigned hi = (unsigned)(unsigned short)f2bf(aB[r]);
          slab[r * 16] = lo | (hi << 16);
        }
      }
    }

    __syncthreads();                             // all stores issued
    if (tid == 0) {
      __threadfence();                           // L2 writeback: cross-XCD visible
      __hip_atomic_store(&flags[t], 1, __ATOMIC_RELEASE, __HIP_MEMORY_SCOPE_AGENT);
    }
    return;
  }

  // =================== rnn role: persistent recurrence ===================
  const int wv = tid >> 6, lane = tid & 63, ln16 = lane & 15, q = lane >> 4;
  const int row4 = lane & 3;            // A-frag source row (m & 3)
  const int wg = blockIdx.x;

  // persistent weight fragments: this wave's 32 cols of each gate.
  // wR,wU pinned resident (128 VGPRs); wH left remat-able (streams from L2
  // each step under phase-A cover).
  short8 wR[2][8], wU[2][8], wH[2][8];
#pragma unroll
  for (int nt = 0; nt < 2; ++nt) {
    int nr = wv * 32 + nt * 16 + ln16;
#pragma unroll
    for (int kk = 0; kk < 8; ++kk) {
      wR[nt][kk] = *(const short8*)(WhB + (((size_t)(nr * 8 + kk) * 4 + q) * 8));
      wU[nt][kk] = *(const short8*)(WhB + (((size_t)((256 + nr) * 8 + kk) * 4 + q) * 8));
      wH[nt][kk] = *(const short8*)(WhB + (((size_t)((512 + nr) * 8 + kk) * 4 + q) * 8));
    }
  }
#pragma unroll
  for (int nt = 0; nt < 2; ++nt)
#pragma unroll
    for (int kk = 0; kk < 8; ++kk) { PIN8(wR[nt][kk]); PIN8(wU[nt][kk]); }

  for (int i = tid; i < 4 * HSTRIDE; i += 512) { hFc[i] = 0; rFc[i] = 0; }

  const floatx4 z4 = {0.f, 0.f, 0.f, 0.f};
  float hq[2] = {0.f, 0.f};             // h(row=q, col = wv*32 + nt*16 + ln16)

  const unsigned* slab0 = pre2 + (size_t)wg * SEQL * 1536;

  acq_spin(&flags[0]);                  // wait for slab 0
  unsigned cur0 = slab0[0 * 512 + tid];
  unsigned cur1 = slab0[1 * 512 + tid];
  unsigned cur2 = slab0[2 * 512 + tid];
  int fcur = __hip_atomic_load(&flags[1], __ATOMIC_RELAXED, __HIP_MEMORY_SCOPE_AGENT);

  float* outBase = out + ((size_t)(wg * 4 + q) * SEQL) * UNITS + wv * 32 + ln16;
  const int aoff = row4 * HSTRIDE + q * 8;       // + kk*32 per step
  const int woff = q * HSTRIDE + wv * 32 + ln16; // + nt*16

  __syncthreads();

  for (int t = 0; t < SEQL; ++t) {
    // issue next-next flag read now; its result is needed only next iter
    int fnxt = 1;
    if (t + 2 < SEQL)
      fnxt = __hip_atomic_load(&flags[t + 2], __ATOMIC_RELAXED, __HIP_MEMORY_SCOPE_AGENT);
    // gate for slab t+1 (value pipelined from last iteration; spin = rare)
    if (t + 1 < SEQL && fcur == 0) acq_spin(&flags[t + 1]);
    asm volatile("" ::: "memory");      // keep prefetch below the gate

    const unsigned* nslab = slab0 + (size_t)(t < SEQL - 1 ? t + 1 : t) * 1536;
    unsigned nxt0 = nslab[0 * 512 + tid];
    unsigned nxt1 = nslab[1 * 512 + tid];
    unsigned nxt2 = nslab[2 * 512 + tid];

    // ---- phase A: r,u pre-acts ----
    floatx4 accR[2], accU[2];
    {
      const short8 a0 = *(const short8*)&hFc[aoff];
      accR[0] = __builtin_amdgcn_mfma_f32_16x16x32_bf16(a0, wR[0][0], z4, 0, 0, 0);
      accR[1] = __builtin_amdgcn_mfma_f32_16x16x32_bf16(a0, wR[1][0], z4, 0, 0, 0);
      accU[0] = __builtin_amdgcn_mfma_f32_16x16x32_bf16(a0, wU[0][0], z4, 0, 0, 0);
      accU[1] = __builtin_amdgcn_mfma_f32_16x16x32_bf16(a0, wU[1][0], z4, 0, 0, 0);
    }
#pragma unroll
    for (int kk = 1; kk < 8; ++kk) {
      const short8 a = *(const short8*)&hFc[aoff + kk * 32];
      accR[0] = __builtin_amdgcn_mfma_f32_16x16x32_bf16(a, wR[0][kk], accR[0], 0, 0, 0);
      accR[1] = __builtin_amdgcn_mfma_f32_16x16x32_bf16(a, wR[1][kk], accR[1], 0, 0, 0);
      accU[0] = __builtin_amdgcn_mfma_f32_16x16x32_bf16(a, wU[0][kk], accU[0], 0, 0, 0);
      accU[1] = __builtin_amdgcn_mfma_f32_16x16x32_bf16(a, wU[1][kk], accU[1], 0, 0, 0);
    }
    float uq[2];
#pragma unroll
    for (int nt = 0; nt < 2; ++nt) {
      float vR = (q == 0) ? accR[nt][0] : (q == 1) ? accR[nt][1]
               : (q == 2) ? accR[nt][2] : accR[nt][3];
      float vU = (q == 0) ? accU[nt][0] : (q == 1) ? accU[nt][1]
               : (q == 2) ? accU[nt][2] : accU[nt][3];
      float pR = bf2f((unsigned short)(nt ? (cur0 >> 16) : (cur0 & 0xffff)));
      float pU = bf2f((unsigned short)(nt ? (cur1 >> 16) : (cur1 & 0xffff)));
      float rg = frcp(1.f + fexp2(vR + pR));
      uq[nt]   = frcp(1.f + fexp2(vU + pU));
      rFc[woff + nt * 16] = f2bf(rg * hq[nt]);
    }
    LDS_BARRIER();

    // ---- phase B: cand, h update ----
    floatx4 accH[2];
    {
      const short8 a0 = *(const short8*)&rFc[aoff];
      accH[0] = __builtin_amdgcn_mfma_f32_16x16x32_bf16(a0, wH[0][0], z4, 0, 0, 0);
      accH[1] = __builtin_amdgcn_mfma_f32_16x16x32_bf16(a0, wH[1][0], z4, 0, 0, 0);
    }
#pragma unroll
    for (int kk = 1; kk < 8; ++kk) {
      const short8 a = *(const short8*)&rFc[aoff + kk * 32];
      accH[0] = __builtin_amdgcn_mfma_f32_16x16x32_bf16(a, wH[0][kk], accH[0], 0, 0, 0);
      accH[1] = __builtin_amdgcn_mfma_f32_16x16x32_bf16(a, wH[1][kk], accH[1], 0, 0, 0);
    }
#pragma unroll
    for (int nt = 0; nt < 2; ++nt) {
      float vH = (q == 0) ? accH[nt][0] : (q == 1) ? accH[nt][1]
               : (q == 2) ? accH[nt][2] : accH[nt][3];
      float pH = bf2f((unsigned short)(nt ? (cur2 >> 16) : (cur2 & 0xffff)));
      float cand = 1.f - 2.f * frcp(1.f + fexp2(vH + pH));   // tanh (scale folded)
      float hnew = uq[nt] * (hq[nt] - cand) + cand;
      hq[nt] = hnew;
      hFc[woff + nt * 16] = f2bf(hnew);
      outBase[(size_t)t * UNITS + nt * 16] = hnew;
    }
    cur0 = nxt0; cur1 = nxt1; cur2 = nxt2; fcur = fnxt;
    LDS_BARRIER();
  }
}

extern "C" void kernel_launch(void* const* d_in, const int* in_sizes, int n_in,
                              void* d_out, int out_size, void* d_ws, size_t ws_size,
                              hipStream_t stream) {
  const float* x    = (const float*)d_in[0];
  const float* iw   = (const float*)d_in[1];
  const float* hw   = (const float*)d_in[2];
  const float* bias = (const float*)d_in[3];
  // d_in[4] (constant) is [I;0] — folded analytically, unused.
  float* out = (float*)d_out;

  unsigned* pre2 = (unsigned*)d_ws;                    // 32*1024*1536 dwords = 192 MB
  const size_t preDwords = (size_t)32 * SEQL * 1536;
  short* WcB = (short*)(pre2 + preDwords);             // 384*768 bf16
  short* WhB = WcB + (size_t)384 * G3;                 // 256*768 bf16
  int* flags = (int*)(WhB + (size_t)256 * G3);         // 1024 ints

  prep_kernel<<<1952, 256, 0, stream>>>(iw, hw, WcB, WhB, flags);
  fused_kernel<<<32 + 1024, 512, 0, stream>>>(x, WcB, bias, pre2, WhB, out, flags);
}